// Round 16
// baseline (303.476 us; speedup 1.0000x reference)
//
#include <hip/hip_runtime.h>
#include <hip/hip_cooperative_groups.h>

namespace cg = cooperative_groups;

struct Params {
  const float *X, *E, *nbr;
  const float *embW, *embB, *boutW, *boutB;
  const float *qpW, *qpB, *kpW, *kpB, *qoW, *qoB, *koW, *koB;
  const float *bpW, *bpB, *bowW, *bowB;
  const float *qlnG, *qlnB, *klnG, *klnB;
  float *out;
  float *pkT;      // [4][512][256] all-layer transposed keys (only cross-block data)
  float *rareRow;  // [65536][128] rare-pair bias rows (own-block use only)
};

__device__ __forceinline__ float mishf(float x) {
  float sp = (x > 20.f) ? x : log1pf(expf(x));
  return x * tanhf(sp);
}

// Full bias pipe for one rare-pair row, one layer (own-block; barriers inside)
__device__ void rare_pipe(float* row, float* drow,
                          const float* __restrict__ Wp, const float* __restrict__ Bp,
                          const float* __restrict__ Wo, const float* __restrict__ Bo,
                          float* smW, float* smS, int t) {
  const int lane = t & 63, wave = t >> 6;
  if (t < 128) smS[t] = row[t];
  __syncthreads();
  { const int o = t & 511, kh = t >> 9;
    const float* Wc = Wp + (kh * 64) * 512 + o;
    const float* rc = smS + kh * 64;
    float a = (kh == 0) ? Bp[o] : 0.f;
    #pragma unroll 8
    for (int c = 0; c < 64; ++c) a = fmaf(rc[c], Wc[c * 512], a);
    smW[t] = a; }
  __syncthreads();
  if (t < 512) smS[128 + t] = smW[t] + smW[512 + t];
  __syncthreads();
  if (wave < 4) {
    float e1 = smS[128 + wave * 128 + lane], e2 = smS[128 + wave * 128 + 64 + lane];
    float s = e1 * e1 + e2 * e2;
    #pragma unroll
    for (int sh = 32; sh; sh >>= 1) s += __shfl_xor(s, sh);
    if (lane == 0) drow[wave] = sqrtf(s);
  }
  { const int c = t & 127, ch = t >> 7;
    const float* Woc = Wo + (ch * 64) * 128 + c;
    const float* bc = smS + 128 + ch * 64;
    float a = 0.f;
    #pragma unroll 8
    for (int o2 = 0; o2 < 64; ++o2) a = fmaf(bc[o2], Woc[o2 * 128], a);
    smW[t] = a; }
  __syncthreads();
  if (t < 128) {
    float a = Bo[t];
    #pragma unroll
    for (int j = 0; j < 8; ++j) a += smW[t + 128 * j];
    row[t] = mishf(a);
  }
  __syncthreads();
}

// 256 blocks x 1024 threads; ONE grid.sync; all per-n state in LDS.
__global__ void __launch_bounds__(1024, 4) crakn(Params P) {
  cg::grid_group grid = cg::this_grid();
  const int b = blockIdx.x, t = threadIdx.x;
  const int lane = t & 63, wave = t >> 6;
  const int n = b;

  // persistent
  __shared__ float smPQ[2048];          // pq for all 4 layers
  __shared__ float smKr[512];           // current pk row
  __shared__ float smQ[64], smKq[64];
  __shared__ float smNbr[256];
  __shared__ int   smMap[256];          // -2 zero-class, -1 gen-class, >=0 rare idx
  __shared__ float smPD[4096];          // rare diffs [pair][layer][head]
  __shared__ float smDiff[32];          // [layer][class][head]
  __shared__ float rowBuf[512];         // [parity][class][128] bias rows
  __shared__ float smPred[1];
  __shared__ int   smI[257];
  __shared__ float smD[256];
  // scratch
  __shared__ float smW[1024];           // bias1 zero partials -> b_z
  __shared__ float smB2[1024];          // bias1 gen partials -> b_g / rare scratch
  __shared__ float smX2[1024];          // bias2 zero partials
  __shared__ float smY2[1024];          // bias2 gen partials
  __shared__ float smZ[1024];           // Bupd partials
  __shared__ float smH[64];

  // ================= Phase A: embed / pred0 / distances =================
  {
    if (t < 256) smB2[t] = P.X[n * 256 + t];
    if (t < 256) smNbr[t] = P.nbr[t];
    if (t == 0) smI[256] = 0;
    __syncthreads();
    { const int d = t & 63, ch = t >> 6;
      const float* W = P.embW + (ch * 16) * 64 + d;
      const float* xr = smB2 + ch * 16;
      float acc = 0.f;
      #pragma unroll
      for (int f = 0; f < 16; ++f) acc = fmaf(xr[f], W[f * 64], acc);
      smW[t] = acc; }
    float pp = (t < 256) ? smB2[t] * P.boutW[t] : 0.f;
    #pragma unroll
    for (int s = 32; s; s >>= 1) pp += __shfl_xor(pp, s);
    if (t < 256 && lane == 0) smH[wave] = pp;
    __syncthreads();
    if (t < 64) {
      float nd = P.embB[t];
      #pragma unroll
      for (int j = 0; j < 16; ++j) nd += smW[t + 64 * j];
      smQ[t] = nd; smKq[t] = nd;
    }
    if (t == 0) smPred[0] = smH[0] + smH[1] + smH[2] + smH[3] + P.boutB[0];
    __syncthreads();
    if (t < 25) ((float4*)(smB2 + 384))[t] = ((const float4*)(P.E + n * 100))[t];
    __syncthreads();
    if (t < 256) {                      // distances, thread = m
      const int m = t;
      const float4* em = (const float4*)(P.E + m * 100);
      const float4* en = (const float4*)(smB2 + 384);
      float sq = 0.f;
      #pragma unroll 5
      for (int jj = 0; jj < 25; ++jj) {
        float4 a = en[jj], c = em[jj];
        float dx = a.x - c.x, dy = a.y - c.y, dz = a.z - c.z, dw = a.w - c.w;
        sq += dx * dx + dy * dy + dz * dz + dw * dw;
      }
      float dd = (sq > 0.f) ? sqrtf(sq) : 0.f;
      // exp(-127*(d-c)^2), c in [0,1]: fp32-underflows to exactly 0 for d>=1.905.
      // d==0 rows identical -> shared zero-class; underflowed -> shared gen-class.
      int mv;
      if (dd == 0.f) mv = -2;
      else if (dd < 1.905f) {
        int i = atomicAdd(&smI[256], 1);
        smI[i] = m; smD[i] = dd;
        mv = i;
      } else mv = -1;
      smMap[m] = mv;
    }
    if (t < 128) {                      // parity-0 rows for both classes
      float c = (float)t * (1.f / 127.f);
      rowBuf[t] = expf(-127.f * c * c); // zero class (d == 0)
      rowBuf[128 + t] = 0.f;            // gen class (underflowed)
    }
    __syncthreads();
    { int cnt = smI[256]; if (cnt > 256) cnt = 256;   // rare RBF rows (none in data)
      for (int i = 0; i < cnt; ++i) if (t < 128) {
        float dd = smD[i] - (float)t * (1.f / 127.f);
        P.rareRow[(size_t)(n * 256 + i) * 128 + t] = expf(-127.f * dd * dd);
      } }
    __syncthreads();
  }

  // ============ Phase 1: q/k chain + bias chains, NO grid syncs ============
  for (int l = 0; l < 4; ++l) {
    const float* rowCur = rowBuf + (l & 1) * 256;
    float* rowNxt = rowBuf + ((l + 1) & 1) * 256;
    // --- S0: JAMMED proj + bias1 partials: two load streams in flight ---
    { const int g = t >> 9, u = t & 511;
      const float* Wp = (g ? P.kpW : P.qpW) + (size_t)l * 32768 + u;
      const float* Wb = P.bpW + (size_t)l * 65536 + (size_t)(g * 64) * 512 + u;
      const float* xs = g ? smKq : smQ;
      const float* rz = rowCur + g * 64;
      const float* rg = rowCur + 128 + g * 64;
      float ap = (g ? P.kpB : P.qpB)[l * 512 + u];
      float az = 0.f, ag = 0.f;
      #pragma unroll 16
      for (int i = 0; i < 64; ++i) {
        float wp = Wp[i * 512];
        float wb = Wb[i * 512];
        ap = fmaf(xs[i], wp, ap);
        az = fmaf(rz[i], wb, az);
        ag = fmaf(rg[i], wb, ag);
      }
      if (g) { smKr[u] = ap; P.pkT[(size_t)l * 131072 + u * 256 + n] = ap; }
      else smPQ[l * 512 + u] = ap;
      smW[t] = az; smB2[t] = ag;
    }
    __syncthreads();
    // --- S1: bias1 reduce -> b_z in smW[0..511], b_g in smB2[0..511] ---
    if (t < 512) {
      float bp = P.bpB[l * 512 + t];
      float bz = smW[t] + smW[512 + t] + bp;
      float bg = smB2[t] + smB2[512 + t] + bp;
      smW[t] = bz; smB2[t] = bg;
    }
    __syncthreads();
    // --- S2: norms + (l<3) JAMMED Bupd + bias2 partials ---
    if (wave < 8) {                     // per-head norms -> smDiff
      const int cls = wave >> 2, h = wave & 3;
      const float* arr = cls ? smB2 : smW;
      float e1 = arr[h * 128 + lane], e2 = arr[h * 128 + 64 + lane];
      float s = e1 * e1 + e2 * e2;
      #pragma unroll
      for (int sh = 32; sh; sh >>= 1) s += __shfl_xor(s, sh);
      if (lane == 0) smDiff[(l * 2 + cls) * 4 + h] = sqrtf(s);
    }
    if (l < 3) {
      { const int g = t >> 9, u = t & 511;
        const int d = u & 63, ch = u >> 6;     // Bupd: out d, K-chunk ch
        const int i = t & 127, kc = t >> 7;    // bias2: out i, K-chunk kc
        const float* prow = g ? smKr : (smPQ + l * 512);
        const float* Wu = (g ? P.koW : P.qoW) + (size_t)l * 32768 + d;
        const float* Wo = P.bowW + (size_t)l * 65536 + (size_t)(kc * 64) * 128 + i;
        const float* bz = smW + kc * 64;
        const float* bg = smB2 + kc * 64;
        float au = 0.f, pz = 0.f, pg = 0.f;
        #pragma unroll 16
        for (int it = 0; it < 64; ++it) {
          const int r = ch * 64 + it;
          float wu = Wu[(size_t)r * 64];
          float wo = Wo[it * 128];
          au = fmaf(prow[((r & 3) << 7) | (r >> 2)], wu, au);
          pz = fmaf(bz[it], wo, pz);
          pg = fmaf(bg[it], wo, pg);
        }
        smZ[t] = au; smX2[t] = pz; smY2[t] = pg;
      }
      __syncthreads();
      // --- S3: rowNxt (t<128) + Bupd reduce/LN ---
      if (t < 128) {
        float bo = P.bowB[l * 128 + t];
        float sz = 0.f, sg = 0.f;
        #pragma unroll
        for (int kc = 0; kc < 8; ++kc) { sz += smX2[kc * 128 + t]; sg += smY2[kc * 128 + t]; }
        rowNxt[t] = mishf(sz + bo);
        rowNxt[128 + t] = mishf(sg + bo);
      }
      { const int g = t >> 9, u = t & 511;
        if (u < 64) {
          float acc = (g ? P.koB : P.qoB)[l * 64 + u];
          #pragma unroll
          for (int j = 0; j < 8; ++j) acc += smZ[g * 512 + u + 64 * j];
          float* x = g ? smKq : smQ;
          float xv = x[u] + mishf(acc);
          float mean = xv;
          #pragma unroll
          for (int s = 32; s; s >>= 1) mean += __shfl_xor(mean, s);
          mean *= (1.f / 64.f);
          float dv = xv - mean, var = dv * dv;
          #pragma unroll
          for (int s = 32; s; s >>= 1) var += __shfl_xor(var, s);
          var *= (1.f / 64.f);
          const float* G  = (g ? P.klnG : P.qlnG) + l * 64;
          const float* Bb = (g ? P.klnB : P.qlnB) + l * 64;
          x[u] = dv * rsqrtf(var + 1e-5f) * G[u] + Bb[u];
        } }
      __syncthreads();
    }
    // rare-pair pipes for layer l (own-block; none in this data)
    { int cnt = smI[256]; if (cnt > 256) cnt = 256;
      if (cnt > 0) {
        __syncthreads();                 // protect smW/smB2 (norms readers) before reuse
        for (int i = 0; i < cnt; ++i)
          rare_pipe(P.rareRow + (size_t)(n * 256 + i) * 128, smPD + i * 16 + l * 4,
                    P.bpW + (size_t)l * 65536, P.bpB + l * 512,
                    P.bowW + (size_t)l * 65536, P.bowB + l * 128, smW, smB2, t);
      } }
  }

  grid.sync();   // the ONLY grid-wide sync: pkT (all layers) now visible

  // ====== Phase 2: ALL (layer, head) attention in parallel ======
  // softmax weights are pred-independent; only the diagonal value carries the
  // pred recursion. Per (l,h): A = sum_{m!=n} e_m*nbr[m], B = e_n, D = sum e.
  {
    const int l = t >> 8, h = (t >> 6) & 3, mq = lane;   // wave = (l,h), lane = mq
    const float* qv = smPQ + l * 512 + h * 128;
    const float4* pt4 = (const float4*)P.pkT + (size_t)l * 32768 + mq;
    float4 dot = {0.f, 0.f, 0.f, 0.f};
    #pragma unroll 8
    for (int j = 0; j < 128; ++j) {
      float a = qv[j];
      float4 v = pt4[(size_t)(h * 128 + j) * 64];
      dot.x = fmaf(a, v.x, dot.x); dot.y = fmaf(a, v.y, dot.y);
      dot.z = fmaf(a, v.z, dot.z); dot.w = fmaf(a, v.w, dot.w);
    }
    float dArr[4] = {dot.x, dot.y, dot.z, dot.w};
    float lg[4], nb[4];
    int self = -1;
    #pragma unroll
    for (int i = 0; i < 4; ++i) {
      const int m = mq * 4 + i;
      const int cls = smMap[m];
      const float bd = (cls == -2) ? smDiff[(l * 2 + 0) * 4 + h]
                     : (cls == -1) ? smDiff[(l * 2 + 1) * 4 + h]
                     : smPD[cls * 16 + l * 4 + h];
      lg[i] = dArr[i] * 0.08838834764831845f + bd;   // 1/sqrt(128)
      nb[i] = smNbr[m];
      if (m == n) { self = i; nb[i] = 0.f; }
    }
    float wm = fmaxf(fmaxf(lg[0], lg[1]), fmaxf(lg[2], lg[3]));
    #pragma unroll
    for (int s = 32; s; s >>= 1) wm = fmaxf(wm, __shfl_xor(wm, s));
    float sA = 0.f, sB = 0.f, sD = 0.f;
    #pragma unroll
    for (int i = 0; i < 4; ++i) {
      float e = expf(lg[i] - wm);
      sD += e;
      sA = fmaf(e, nb[i], sA);
      if (i == self) sB = e;
    }
    #pragma unroll
    for (int s = 32; s; s >>= 1) {
      sA += __shfl_xor(sA, s); sB += __shfl_xor(sB, s); sD += __shfl_xor(sD, s);
    }
    if (lane == 0) { smH[wave] = sA; smH[16 + wave] = sB; smH[32 + wave] = sD; }
  }
  __syncthreads();
  if (t == 0) {                         // serial pred chain over layers
    float p = smPred[0];
    #pragma unroll
    for (int l = 0; l < 4; ++l) {
      float np = 0.f;
      #pragma unroll
      for (int h = 0; h < 4; ++h) {
        const int w = l * 4 + h;
        np += 0.25f * ((smH[w] + smH[16 + w] * p) / smH[32 + w]);
      }
      p = np;
    }
    P.out[n] = p;
  }
}

// ---------------------------------------------------------------------------
extern "C" void kernel_launch(void* const* d_in, const int* in_sizes, int n_in,
                              void* d_out, int out_size, void* d_ws, size_t ws_size,
                              hipStream_t stream) {
  char* p = (char*)d_ws;
  auto carve = [&](size_t bytes) -> void* {
    void* r = (void*)p;
    p += (bytes + 255) & ~(size_t)255;
    return r;
  };

  Params P;
  P.X     = (const float*)d_in[0];
  P.E     = (const float*)d_in[1];
  P.nbr   = (const float*)d_in[2];
  P.embW  = (const float*)d_in[3];
  P.embB  = (const float*)d_in[4];
  P.boutW = (const float*)d_in[5];
  P.boutB = (const float*)d_in[6];
  P.qpW   = (const float*)d_in[7];
  P.qpB   = (const float*)d_in[8];
  P.kpW   = (const float*)d_in[9];
  P.kpB   = (const float*)d_in[10];
  P.qoW   = (const float*)d_in[11];
  P.qoB   = (const float*)d_in[12];
  P.koW   = (const float*)d_in[13];
  P.koB   = (const float*)d_in[14];
  P.bpW   = (const float*)d_in[15];
  P.bpB   = (const float*)d_in[16];
  P.bowW  = (const float*)d_in[17];
  P.bowB  = (const float*)d_in[18];
  P.qlnG  = (const float*)d_in[19];
  P.qlnB  = (const float*)d_in[20];
  P.klnG  = (const float*)d_in[21];
  P.klnB  = (const float*)d_in[22];
  P.out   = (float*)d_out;

  P.pkT     = (float*)carve((size_t)4 * 512 * 256 * 4);
  P.rareRow = (float*)carve((size_t)65536 * 128 * 4);

  void* args[] = { &P };
  hipLaunchCooperativeKernel((const void*)crakn, dim3(256), dim3(1024), args, 0, stream);
}

// Round 17
// 225.795 us; speedup vs baseline: 1.3440x; 1.3440x over previous
//
#include <hip/hip_runtime.h>
#include <hip/hip_cooperative_groups.h>

namespace cg = cooperative_groups;

struct Params {
  const float *X, *E, *nbr;
  const float *embW, *embB, *boutW, *boutB;
  const float *qpW, *qpB, *kpW, *kpB, *qoW, *qoB, *koW, *koB;
  const float *bpW, *bpB, *bowW, *bowB;
  const float *qlnG, *qlnB, *klnG, *klnB;
  float *out;
  float *pkT;      // [4][512][256] all-layer transposed keys (only cross-block data)
  float *rareRow;  // [65536][128] rare-pair bias rows (own-block use only)
};

__device__ __forceinline__ float mishf(float x) {
  float sp = (x > 20.f) ? x : log1pf(expf(x));
  return x * tanhf(sp);
}

// Full bias pipe for one rare-pair row, one layer (own-block; barriers inside)
__device__ void rare_pipe(float* row, float* drow,
                          const float* __restrict__ Wp, const float* __restrict__ Bp,
                          const float* __restrict__ Wo, const float* __restrict__ Bo,
                          float* smW, float* smS, int t) {
  const int lane = t & 63, wave = t >> 6;
  if (t < 128) smS[t] = row[t];
  __syncthreads();
  { const int o = t & 511, kh = t >> 9;
    const float* Wc = Wp + (kh * 64) * 512 + o;
    const float* rc = smS + kh * 64;
    float a = (kh == 0) ? Bp[o] : 0.f;
    #pragma unroll 8
    for (int c = 0; c < 64; ++c) a = fmaf(rc[c], Wc[c * 512], a);
    smW[t] = a; }
  __syncthreads();
  if (t < 512) smS[128 + t] = smW[t] + smW[512 + t];
  __syncthreads();
  if (wave < 4) {
    float e1 = smS[128 + wave * 128 + lane], e2 = smS[128 + wave * 128 + 64 + lane];
    float s = e1 * e1 + e2 * e2;
    #pragma unroll
    for (int sh = 32; sh; sh >>= 1) s += __shfl_xor(s, sh);
    if (lane == 0) drow[wave] = sqrtf(s);
  }
  { const int c = t & 127, ch = t >> 7;
    const float* Woc = Wo + (ch * 64) * 128 + c;
    const float* bc = smS + 128 + ch * 64;
    float a = 0.f;
    #pragma unroll 8
    for (int o2 = 0; o2 < 64; ++o2) a = fmaf(bc[o2], Woc[o2 * 128], a);
    smW[t] = a; }
  __syncthreads();
  if (t < 128) {
    float a = Bo[t];
    #pragma unroll
    for (int j = 0; j < 8; ++j) a += smW[t + 128 * j];
    row[t] = mishf(a);
  }
  __syncthreads();
}

// 256 blocks x 1024 threads; ONE grid.sync; all per-n state in LDS.
__global__ void __launch_bounds__(1024, 4) crakn(Params P) {
  cg::grid_group grid = cg::this_grid();
  const int b = blockIdx.x, t = threadIdx.x;
  const int lane = t & 63, wave = t >> 6;
  const int n = b;

  // persistent
  __shared__ float smPQ[2048];          // pq for all 4 layers
  __shared__ float smKr[512];           // current pk row
  __shared__ float smQ[64], smKq[64];
  __shared__ float smNbr[256];
  __shared__ int   smMap[256];          // -2 zero-class, -1 gen-class, >=0 rare idx
  __shared__ float smPD[4096];          // rare diffs [pair][layer][head]
  __shared__ float smDiff[32];          // [layer][class][head]
  __shared__ float rowBuf[512];         // [parity][class][128] bias rows
  __shared__ float smPred[1];
  __shared__ int   smI[257];
  __shared__ float smD[256];
  // scratch
  __shared__ float smW[1024];           // bias1 zero partials -> b_z
  __shared__ float smB2[1024];          // bias1 gen partials -> b_g / rare scratch
  __shared__ float smX2[1024];          // bias2 zero partials
  __shared__ float smY2[1024];          // bias2 gen partials
  __shared__ float smZ[1024];           // Bupd partials
  __shared__ float smH[64];

  // ================= Phase A: embed / pred0 / distances =================
  {
    if (t < 256) smB2[t] = P.X[n * 256 + t];
    if (t < 256) smNbr[t] = P.nbr[t];
    if (t == 0) smI[256] = 0;
    __syncthreads();
    { const int d = t & 63, ch = t >> 6;
      const float* W = P.embW + (ch * 16) * 64 + d;
      const float* xr = smB2 + ch * 16;
      float acc = 0.f;
      #pragma unroll
      for (int f = 0; f < 16; ++f) acc = fmaf(xr[f], W[f * 64], acc);
      smW[t] = acc; }
    float pp = (t < 256) ? smB2[t] * P.boutW[t] : 0.f;
    #pragma unroll
    for (int s = 32; s; s >>= 1) pp += __shfl_xor(pp, s);
    if (t < 256 && lane == 0) smH[wave] = pp;
    __syncthreads();
    if (t < 64) {
      float nd = P.embB[t];
      #pragma unroll
      for (int j = 0; j < 16; ++j) nd += smW[t + 64 * j];
      smQ[t] = nd; smKq[t] = nd;
    }
    if (t == 0) smPred[0] = smH[0] + smH[1] + smH[2] + smH[3] + P.boutB[0];
    __syncthreads();
    if (t < 25) ((float4*)(smB2 + 384))[t] = ((const float4*)(P.E + n * 100))[t];
    __syncthreads();
    if (t < 256) {                      // distances, thread = m
      const int m = t;
      const float4* em = (const float4*)(P.E + m * 100);
      const float4* en = (const float4*)(smB2 + 384);
      float sq = 0.f;
      #pragma unroll 5
      for (int jj = 0; jj < 25; ++jj) {
        float4 a = en[jj], c = em[jj];
        float dx = a.x - c.x, dy = a.y - c.y, dz = a.z - c.z, dw = a.w - c.w;
        sq += dx * dx + dy * dy + dz * dz + dw * dw;
      }
      float dd = (sq > 0.f) ? sqrtf(sq) : 0.f;
      // exp(-127*(d-c)^2), c in [0,1]: fp32-underflows to exactly 0 for d>=1.905.
      // d==0 rows identical -> shared zero-class; underflowed -> shared gen-class.
      int mv;
      if (dd == 0.f) mv = -2;
      else if (dd < 1.905f) {
        int i = atomicAdd(&smI[256], 1);
        smI[i] = m; smD[i] = dd;
        mv = i;
      } else mv = -1;
      smMap[m] = mv;
    }
    if (t < 128) {                      // parity-0 rows for both classes
      float c = (float)t * (1.f / 127.f);
      rowBuf[t] = expf(-127.f * c * c); // zero class (d == 0)
      rowBuf[128 + t] = 0.f;            // gen class (underflowed)
    }
    __syncthreads();
    { int cnt = smI[256]; if (cnt > 256) cnt = 256;   // rare RBF rows (none in data)
      for (int i = 0; i < cnt; ++i) if (t < 128) {
        float dd = smD[i] - (float)t * (1.f / 127.f);
        P.rareRow[(size_t)(n * 256 + i) * 128 + t] = expf(-127.f * dd * dd);
      } }
    __syncthreads();
  }

  // ============ Phase 1: q/k chain + bias chains, NO grid syncs ============
  for (int l = 0; l < 4; ++l) {
    const float* rowCur = rowBuf + (l & 1) * 256;
    float* rowNxt = rowBuf + ((l + 1) & 1) * 256;
    // --- S0: JAMMED proj + bias1 partials: two load streams in flight ---
    { const int g = t >> 9, u = t & 511;
      const float* Wp = (g ? P.kpW : P.qpW) + (size_t)l * 32768 + u;
      const float* Wb = P.bpW + (size_t)l * 65536 + (size_t)(g * 64) * 512 + u;
      const float* xs = g ? smKq : smQ;
      const float* rz = rowCur + g * 64;
      const float* rg = rowCur + 128 + g * 64;
      float ap = (g ? P.kpB : P.qpB)[l * 512 + u];
      float az = 0.f, ag = 0.f;
      #pragma unroll 8
      for (int i = 0; i < 64; ++i) {
        float wp = Wp[i * 512];
        float wb = Wb[i * 512];
        ap = fmaf(xs[i], wp, ap);
        az = fmaf(rz[i], wb, az);
        ag = fmaf(rg[i], wb, ag);
      }
      if (g) { smKr[u] = ap; P.pkT[(size_t)l * 131072 + u * 256 + n] = ap; }
      else smPQ[l * 512 + u] = ap;
      smW[t] = az; smB2[t] = ag;
    }
    __syncthreads();
    // --- S1: bias1 reduce -> b_z in smW[0..511], b_g in smB2[0..511] ---
    if (t < 512) {
      float bp = P.bpB[l * 512 + t];
      float bz = smW[t] + smW[512 + t] + bp;
      float bg = smB2[t] + smB2[512 + t] + bp;
      smW[t] = bz; smB2[t] = bg;
    }
    __syncthreads();
    // --- S2: norms + (l<3) JAMMED Bupd + bias2 partials ---
    if (wave < 8) {                     // per-head norms -> smDiff
      const int cls = wave >> 2, h = wave & 3;
      const float* arr = cls ? smB2 : smW;
      float e1 = arr[h * 128 + lane], e2 = arr[h * 128 + 64 + lane];
      float s = e1 * e1 + e2 * e2;
      #pragma unroll
      for (int sh = 32; sh; sh >>= 1) s += __shfl_xor(s, sh);
      if (lane == 0) smDiff[(l * 2 + cls) * 4 + h] = sqrtf(s);
    }
    if (l < 3) {
      { const int g = t >> 9, u = t & 511;
        const int d = u & 63, ch = u >> 6;     // Bupd: out d, K-chunk ch
        const int i = t & 127, kc = t >> 7;    // bias2: out i, K-chunk kc
        const float* prow = g ? smKr : (smPQ + l * 512);
        const float* Wu = (g ? P.koW : P.qoW) + (size_t)l * 32768 + d;
        const float* Wo = P.bowW + (size_t)l * 65536 + (size_t)(kc * 64) * 128 + i;
        const float* bz = smW + kc * 64;
        const float* bg = smB2 + kc * 64;
        float au = 0.f, pz = 0.f, pg = 0.f;
        #pragma unroll 8
        for (int it = 0; it < 64; ++it) {
          const int r = ch * 64 + it;
          float wu = Wu[(size_t)r * 64];
          float wo = Wo[it * 128];
          au = fmaf(prow[((r & 3) << 7) | (r >> 2)], wu, au);
          pz = fmaf(bz[it], wo, pz);
          pg = fmaf(bg[it], wo, pg);
        }
        smZ[t] = au; smX2[t] = pz; smY2[t] = pg;
      }
      __syncthreads();
      // --- S3: rowNxt (t<128) + Bupd reduce/LN ---
      if (t < 128) {
        float bo = P.bowB[l * 128 + t];
        float sz = 0.f, sg = 0.f;
        #pragma unroll
        for (int kc = 0; kc < 8; ++kc) { sz += smX2[kc * 128 + t]; sg += smY2[kc * 128 + t]; }
        rowNxt[t] = mishf(sz + bo);
        rowNxt[128 + t] = mishf(sg + bo);
      }
      { const int g = t >> 9, u = t & 511;
        if (u < 64) {
          float acc = (g ? P.koB : P.qoB)[l * 64 + u];
          #pragma unroll
          for (int j = 0; j < 8; ++j) acc += smZ[g * 512 + u + 64 * j];
          float* x = g ? smKq : smQ;
          float xv = x[u] + mishf(acc);
          float mean = xv;
          #pragma unroll
          for (int s = 32; s; s >>= 1) mean += __shfl_xor(mean, s);
          mean *= (1.f / 64.f);
          float dv = xv - mean, var = dv * dv;
          #pragma unroll
          for (int s = 32; s; s >>= 1) var += __shfl_xor(var, s);
          var *= (1.f / 64.f);
          const float* G  = (g ? P.klnG : P.qlnG) + l * 64;
          const float* Bb = (g ? P.klnB : P.qlnB) + l * 64;
          x[u] = dv * rsqrtf(var + 1e-5f) * G[u] + Bb[u];
        } }
      __syncthreads();
    }
    // rare-pair pipes for layer l (own-block; none in this data)
    { int cnt = smI[256]; if (cnt > 256) cnt = 256;
      if (cnt > 0) {
        __syncthreads();                 // protect smW/smB2 (norms readers) before reuse
        for (int i = 0; i < cnt; ++i)
          rare_pipe(P.rareRow + (size_t)(n * 256 + i) * 128, smPD + i * 16 + l * 4,
                    P.bpW + (size_t)l * 65536, P.bpB + l * 512,
                    P.bowW + (size_t)l * 65536, P.bowB + l * 128, smW, smB2, t);
      } }
  }

  grid.sync();   // the ONLY grid-wide sync: pkT (all layers) now visible

  // ====== Phase 2: ALL (layer, head) attention in parallel ======
  // softmax weights are pred-independent; only the diagonal value carries the
  // pred recursion. Per (l,h): A = sum_{m!=n} e_m*nbr[m], B = e_n, D = sum e.
  {
    const int l = t >> 8, h = (t >> 6) & 3, mq = lane;   // wave = (l,h), lane = mq
    const float* qv = smPQ + l * 512 + h * 128;
    const float4* pt4 = (const float4*)P.pkT + (size_t)l * 32768 + mq;
    float4 dot = {0.f, 0.f, 0.f, 0.f};
    #pragma unroll 8
    for (int j = 0; j < 128; ++j) {
      float a = qv[j];
      float4 v = pt4[(size_t)(h * 128 + j) * 64];
      dot.x = fmaf(a, v.x, dot.x); dot.y = fmaf(a, v.y, dot.y);
      dot.z = fmaf(a, v.z, dot.z); dot.w = fmaf(a, v.w, dot.w);
    }
    float dArr[4] = {dot.x, dot.y, dot.z, dot.w};
    float lg[4], nb[4];
    int self = -1;
    #pragma unroll
    for (int i = 0; i < 4; ++i) {
      const int m = mq * 4 + i;
      const int cls = smMap[m];
      const float bd = (cls == -2) ? smDiff[(l * 2 + 0) * 4 + h]
                     : (cls == -1) ? smDiff[(l * 2 + 1) * 4 + h]
                     : smPD[cls * 16 + l * 4 + h];
      lg[i] = dArr[i] * 0.08838834764831845f + bd;   // 1/sqrt(128)
      nb[i] = smNbr[m];
      if (m == n) { self = i; nb[i] = 0.f; }
    }
    float wm = fmaxf(fmaxf(lg[0], lg[1]), fmaxf(lg[2], lg[3]));
    #pragma unroll
    for (int s = 32; s; s >>= 1) wm = fmaxf(wm, __shfl_xor(wm, s));
    float sA = 0.f, sB = 0.f, sD = 0.f;
    #pragma unroll
    for (int i = 0; i < 4; ++i) {
      float e = expf(lg[i] - wm);
      sD += e;
      sA = fmaf(e, nb[i], sA);
      if (i == self) sB = e;
    }
    #pragma unroll
    for (int s = 32; s; s >>= 1) {
      sA += __shfl_xor(sA, s); sB += __shfl_xor(sB, s); sD += __shfl_xor(sD, s);
    }
    if (lane == 0) { smH[wave] = sA; smH[16 + wave] = sB; smH[32 + wave] = sD; }
  }
  __syncthreads();
  if (t == 0) {                         // serial pred chain over layers
    float p = smPred[0];
    #pragma unroll
    for (int l = 0; l < 4; ++l) {
      float np = 0.f;
      #pragma unroll
      for (int h = 0; h < 4; ++h) {
        const int w = l * 4 + h;
        np += 0.25f * ((smH[w] + smH[16 + w] * p) / smH[32 + w]);
      }
      p = np;
    }
    P.out[n] = p;
  }
}

// ---------------------------------------------------------------------------
extern "C" void kernel_launch(void* const* d_in, const int* in_sizes, int n_in,
                              void* d_out, int out_size, void* d_ws, size_t ws_size,
                              hipStream_t stream) {
  char* p = (char*)d_ws;
  auto carve = [&](size_t bytes) -> void* {
    void* r = (void*)p;
    p += (bytes + 255) & ~(size_t)255;
    return r;
  };

  Params P;
  P.X     = (const float*)d_in[0];
  P.E     = (const float*)d_in[1];
  P.nbr   = (const float*)d_in[2];
  P.embW  = (const float*)d_in[3];
  P.embB  = (const float*)d_in[4];
  P.boutW = (const float*)d_in[5];
  P.boutB = (const float*)d_in[6];
  P.qpW   = (const float*)d_in[7];
  P.qpB   = (const float*)d_in[8];
  P.kpW   = (const float*)d_in[9];
  P.kpB   = (const float*)d_in[10];
  P.qoW   = (const float*)d_in[11];
  P.qoB   = (const float*)d_in[12];
  P.koW   = (const float*)d_in[13];
  P.koB   = (const float*)d_in[14];
  P.bpW   = (const float*)d_in[15];
  P.bpB   = (const float*)d_in[16];
  P.bowW  = (const float*)d_in[17];
  P.bowB  = (const float*)d_in[18];
  P.qlnG  = (const float*)d_in[19];
  P.qlnB  = (const float*)d_in[20];
  P.klnG  = (const float*)d_in[21];
  P.klnB  = (const float*)d_in[22];
  P.out   = (float*)d_out;

  P.pkT     = (float*)carve((size_t)4 * 512 * 256 * 4);
  P.rareRow = (float*)carve((size_t)65536 * 128 * 4);

  void* args[] = { &P };
  hipLaunchCooperativeKernel((const void*)crakn, dim3(256), dim3(1024), args, 0, stream);
}